// Round 9
// baseline (273.831 us; speedup 1.0000x reference)
//
#include <hip/hip_runtime.h>
#include <hip/hip_bf16.h>
#include <cstddef>

// MHA: B=2, N=4096, E=512, H=8, D=64.
// proj v5 (128x64 tile, BK=64, dbuf LDS, XCD-locality swizzle: all 8 n-tiles
// of an m-tile land on one XCD -> X row-panel read once per XCD L2) ->
// flash v8 (unchanged: 32q/wave, 2 blocks/CU, reg-prefetch + ds_write staging,
// stride-72 LDS, no-max softmax, Q pre-scaled by 0.125*log2e) -> final proj.
// All buffers plain layout: Qp/Kp [B,H,N,D], Vt [B,H,D,N], Oc [B,N,E].

typedef __bf16 bf16_t;
typedef __bf16 bf16x8 __attribute__((ext_vector_type(8)));
typedef __bf16 bf16x4 __attribute__((ext_vector_type(4)));
typedef float  f32x4  __attribute__((ext_vector_type(4)));

#define MFMA_BF16 __builtin_amdgcn_mfma_f32_16x16x32_bf16

static __device__ __forceinline__ bf16x8 cvt2(const float4& a, const float4& b) {
  return bf16x8{(bf16_t)a.x,(bf16_t)a.y,(bf16_t)a.z,(bf16_t)a.w,
                (bf16_t)b.x,(bf16_t)b.y,(bf16_t)b.z,(bf16_t)b.w};
}

// ---------------------------------------------------------------------------
// proj_gemm v5: C[8192 x 512] = X @ W^T + bias (*scale). Tile 128x64, BK=64,
// 256 thr (4 waves, each a 64x32 quadrant), double-buffered padded LDS
// (stride 72). 1-D grid of 512 blocks with XCD swizzle:
//   mtile = ((l>>6)<<3)|(l&7), ntile = (l>>3)&7
// -> the 8 ntile-blocks sharing an X row-panel have equal l%8 (same XCD),
// per-XCD L2 set = 8 panels (2 MB) + W (1 MB). 2 blocks/CU, 8 waves/CU.
// MODE 0: bf16 out [B,H,N,D] (Q,K)   MODE 1: bf16 out [B,H,D,N] (V)
// MODE 2: f32 out [B,N,E] (final projection; X is bf16)
// ---------------------------------------------------------------------------
template<bool XF32, int MODE>
__global__ void __launch_bounds__(256, 2)
proj_gemm(const void* __restrict__ Xv, const float* __restrict__ W,
          const float* __restrict__ bias, void* __restrict__ outv, float scale)
{
  __shared__ __align__(16) bf16_t As[2][128 * 72];
  __shared__ __align__(16) bf16_t Bs[2][64 * 72];
  const int l     = blockIdx.x;              // 0..511
  const int mtile = ((l >> 6) << 3) | (l & 7);   // 0..63 (128 rows)
  const int ntile = (l >> 3) & 7;                // 0..7  (64 cols)
  const int tid   = threadIdx.x;
  const int w     = tid >> 6;
  const int lane  = tid & 63;
  const int lr    = lane & 15;
  const int quad  = lane >> 4;
  const int wm    = w & 1;           // m-half (64 rows)
  const int wn    = w >> 1;          // n-half (32 cols)
  const int xrow  = tid >> 1, xcol = (tid & 1) << 5;   // 32 elems per thread
  const int wrow  = tid >> 2, wcol = (tid & 3) << 4;   // 16 elems per thread

  const float*  Xf = (const float*)Xv;
  const bf16_t* Xb = (const bf16_t*)Xv;

  float bvv[2];
#pragma unroll
  for (int ci = 0; ci < 2; ++ci) bvv[ci] = bias[ntile * 64 + wn * 32 + ci * 16 + lr];

  f32x4 acc[4][2] = {};

  float4 xa[8], wa[4];
  bf16x8 xb[4];

  // ---- prologue: load k0=0 ----
#pragma unroll
  for (int j = 0; j < 4; ++j) {
    if constexpr (XF32) {
      const float* p = Xf + (size_t)(mtile * 128 + xrow) * 512 + xcol + j * 8;
      xa[2*j]   = *(const float4*)p;
      xa[2*j+1] = *(const float4*)(p + 4);
    } else {
      xb[j] = *(const bf16x8*)(Xb + (size_t)(mtile * 128 + xrow) * 512 + xcol + j * 8);
    }
  }
#pragma unroll
  for (int j = 0; j < 2; ++j) {
    const float* pw = W + (size_t)(ntile * 64 + wrow) * 512 + wcol + j * 8;
    wa[2*j]   = *(const float4*)pw;
    wa[2*j+1] = *(const float4*)(pw + 4);
  }
#pragma unroll
  for (int j = 0; j < 4; ++j)
    *(bf16x8*)(&As[0][xrow * 72 + xcol + j * 8]) =
        XF32 ? cvt2(xa[2*j], xa[2*j+1]) : xb[j];
#pragma unroll
  for (int j = 0; j < 2; ++j)
    *(bf16x8*)(&Bs[0][wrow * 72 + wcol + j * 8]) = cvt2(wa[2*j], wa[2*j+1]);
  __syncthreads();

  for (int it = 0; it < 8; ++it) {
    const int cur = it & 1, nxt = cur ^ 1;
    // ---- issue next k-block's global loads (into registers) ----
    if (it != 7) {
      const int k0 = (it + 1) << 6;
#pragma unroll
      for (int j = 0; j < 4; ++j) {
        if constexpr (XF32) {
          const float* p = Xf + (size_t)(mtile * 128 + xrow) * 512 + k0 + xcol + j * 8;
          xa[2*j]   = *(const float4*)p;
          xa[2*j+1] = *(const float4*)(p + 4);
        } else {
          xb[j] = *(const bf16x8*)(Xb + (size_t)(mtile * 128 + xrow) * 512 + k0 + xcol + j * 8);
        }
      }
#pragma unroll
      for (int j = 0; j < 2; ++j) {
        const float* pw = W + (size_t)(ntile * 64 + wrow) * 512 + k0 + wcol + j * 8;
        wa[2*j]   = *(const float4*)pw;
        wa[2*j+1] = *(const float4*)(pw + 4);
      }
    }
    // ---- fragments + MFMA on cur ----
    bf16x8 af[4][2], bfr[2][2];
#pragma unroll
    for (int mi = 0; mi < 4; ++mi)
#pragma unroll
      for (int kh = 0; kh < 2; ++kh)
        af[mi][kh] = *(const bf16x8*)(&As[cur][(wm * 64 + mi * 16 + lr) * 72 + (kh * 4 + quad) * 8]);
#pragma unroll
    for (int ci = 0; ci < 2; ++ci)
#pragma unroll
      for (int kh = 0; kh < 2; ++kh)
        bfr[ci][kh] = *(const bf16x8*)(&Bs[cur][(wn * 32 + ci * 16 + lr) * 72 + (kh * 4 + quad) * 8]);
#pragma unroll
    for (int mi = 0; mi < 4; ++mi)
#pragma unroll
      for (int ci = 0; ci < 2; ++ci) {
        acc[mi][ci] = MFMA_BF16(af[mi][0], bfr[ci][0], acc[mi][ci], 0, 0, 0);
        acc[mi][ci] = MFMA_BF16(af[mi][1], bfr[ci][1], acc[mi][ci], 0, 0, 0);
      }
    // ---- convert + write next buffer ----
    if (it != 7) {
#pragma unroll
      for (int j = 0; j < 4; ++j)
        *(bf16x8*)(&As[nxt][xrow * 72 + xcol + j * 8]) =
            XF32 ? cvt2(xa[2*j], xa[2*j+1]) : xb[j];
#pragma unroll
      for (int j = 0; j < 2; ++j)
        *(bf16x8*)(&Bs[nxt][wrow * 72 + wcol + j * 8]) = cvt2(wa[2*j], wa[2*j+1]);
    }
    __syncthreads();
  }

  // C/D layout: col = lane&15 (n), row = quad*4 + reg (m)
#pragma unroll
  for (int mi = 0; mi < 4; ++mi) {
    const int gm0 = mtile * 128 + wm * 64 + mi * 16 + quad * 4;
#pragma unroll
    for (int ci = 0; ci < 2; ++ci) {
      const int gc = ntile * 64 + wn * 32 + ci * 16 + lr;
      if constexpr (MODE == 0) {
        bf16_t* out = (bf16_t*)outv;
        const int h = gc >> 6, dd = gc & 63;
#pragma unroll
        for (int r = 0; r < 4; ++r) {
          const int gm = gm0 + r;
          const int b = gm >> 12, n = gm & 4095;
          out[(size_t)((b * 8 + h) * 4096 + n) * 64 + dd] =
              (bf16_t)((acc[mi][ci][r] + bvv[ci]) * scale);
        }
      } else if constexpr (MODE == 1) {
        bf16_t* out = (bf16_t*)outv;
        const int h = gc >> 6, dd = gc & 63;
        const int b = gm0 >> 12, n0 = gm0 & 4095;  // 4 consecutive n, same b
        bf16x4 pk;
#pragma unroll
        for (int r = 0; r < 4; ++r) pk[r] = (bf16_t)(acc[mi][ci][r] + bvv[ci]);
        *(bf16x4*)(out + (size_t)((b * 8 + h) * 64 + dd) * 4096 + n0) = pk;
      } else {
        float* out = (float*)outv;
#pragma unroll
        for (int r = 0; r < 4; ++r)
          out[(size_t)(gm0 + r) * 512 + gc] = acc[mi][ci][r] + bvv[ci];
      }
    }
  }
}

// ---------------------------------------------------------------------------
// flash_attn v8 (unchanged from R8, measured 102 us, LDS-pipe-bound):
// 256 thr = 4 waves, each wave 32 q-rows; grid (16,32) -> 2 blocks/CU,
// 8 waves/CU; all blocks of head bh land on XCD bh%8 (KV L2-resident).
// KV chunk 64 double-buffered via register-prefetch + ds_write (stride 72).
// Transposed S (S^T = K @ Q^T), fixed m=0 softmax, wave-private P buffer.
// ---------------------------------------------------------------------------
__global__ void __launch_bounds__(256, 2)
flash_attn(const bf16_t* __restrict__ Qp, const bf16_t* __restrict__ Kp,
           const bf16_t* __restrict__ Vt, bf16_t* __restrict__ Oc)
{
  __shared__ __align__(16) bf16_t Klds[2][64 * 72];  // [kv][d], 9 KB each
  __shared__ __align__(16) bf16_t Vlds[2][64 * 72];  // [d][kv], 9 KB each
  __shared__ __align__(16) bf16_t Pl[4][32 * 72];    // per-wave, padded

  const int tid  = threadIdx.x;
  const int w    = tid >> 6;                 // wave 0..3
  const int lane = tid & 63, lr = lane & 15, quad = lane >> 4;
  const int bh   = blockIdx.x;               // 0..15
  const int qt0  = blockIdx.y * 128 + w * 32;

  const bf16_t* Qh = Qp + (size_t)bh * 4096 * 64;
  const bf16_t* Kh = Kp + (size_t)bh * 4096 * 64;
  const bf16_t* Vh = Vt + (size_t)bh * 64 * 4096;

  const int srow = w * 16 + (lane >> 2);
  const int scol = (lane & 3) << 4;

  // Q B-frags for S^T: B[k=d][n=q]
  bf16x8 qf[2][2];
#pragma unroll
  for (int qi = 0; qi < 2; ++qi)
#pragma unroll
    for (int kh = 0; kh < 2; ++kh)
      qf[qi][kh] = *(const bf16x8*)(Qh + (size_t)(qt0 + qi * 16 + lr) * 64 + kh * 32 + quad * 8);

  bf16x8 kst[2], vst[2];
#pragma unroll
  for (int j = 0; j < 2; ++j) {
    kst[j] = *(const bf16x8*)(Kh + (size_t)srow * 64 + scol + j * 8);
    vst[j] = *(const bf16x8*)(Vh + (size_t)srow * 4096 + scol + j * 8);
  }
#pragma unroll
  for (int j = 0; j < 2; ++j) {
    *(bf16x8*)(&Klds[0][srow * 72 + scol + j * 8]) = kst[j];
    *(bf16x8*)(&Vlds[0][srow * 72 + scol + j * 8]) = vst[j];
  }
  __syncthreads();

  f32x4 acc[2][4] = {};        // O C-layout: [qi][d-tile t]
  float lsum[2] = {0.f, 0.f};  // per-lane partials, q = qi*16+lr
  const f32x4 zero = {0.f, 0.f, 0.f, 0.f};
  bf16_t* Pw = &Pl[w][0];

  for (int it = 0; it < 64; ++it) {
    const int cur = it & 1, nxt = cur ^ 1;

    // ---- prefetch next chunk into registers ----
    if (it != 63) {
      const int kvn = (it + 1) << 6;
#pragma unroll
      for (int j = 0; j < 2; ++j) {
        kst[j] = *(const bf16x8*)(Kh + (size_t)(kvn + srow) * 64 + scol + j * 8);
        vst[j] = *(const bf16x8*)(Vh + (size_t)srow * 4096 + kvn + scol + j * 8);
      }
    }

    // ---- K/V fragments (stride 72 -> 2-way banks) ----
    bf16x8 kf[4][2];  // A[m=kv=mt*16+lr][k=d=(kh*4+quad)*8+j]
#pragma unroll
    for (int mt = 0; mt < 4; ++mt)
#pragma unroll
      for (int kh = 0; kh < 2; ++kh)
        kf[mt][kh] = *(const bf16x8*)(&Klds[cur][(mt * 16 + lr) * 72 + (kh * 4 + quad) * 8]);
    bf16x8 vf[4][2];  // B[k=kv=(kvh*4+quad)*8+j][n=d=t*16+lr]
#pragma unroll
    for (int t = 0; t < 4; ++t)
#pragma unroll
      for (int kvh = 0; kvh < 2; ++kvh)
        vf[t][kvh] = *(const bf16x8*)(&Vlds[cur][(t * 16 + lr) * 72 + (kvh * 4 + quad) * 8]);

    // ---- S^T = K @ Q^T : D[m=kv][n=q], 16 MFMAs ----
    f32x4 sT[4][2];
#pragma unroll
    for (int mt = 0; mt < 4; ++mt)
#pragma unroll
      for (int qi = 0; qi < 2; ++qi) {
        sT[mt][qi] = MFMA_BF16(kf[mt][0], qf[qi][0], zero, 0, 0, 0);
        sT[mt][qi] = MFMA_BF16(kf[mt][1], qf[qi][1], sT[mt][qi], 0, 0, 0);
      }

    // ---- p = exp2(sT); transpose P^T(C-layout) -> P(A-layout) via LDS ----
#pragma unroll
    for (int mt = 0; mt < 4; ++mt)
#pragma unroll
      for (int qi = 0; qi < 2; ++qi) {
        float p0 = __builtin_amdgcn_exp2f(sT[mt][qi][0]);
        float p1 = __builtin_amdgcn_exp2f(sT[mt][qi][1]);
        float p2 = __builtin_amdgcn_exp2f(sT[mt][qi][2]);
        float p3 = __builtin_amdgcn_exp2f(sT[mt][qi][3]);
        lsum[qi] += (p0 + p1) + (p2 + p3);
        bf16x4 pk = {(bf16_t)p0, (bf16_t)p1, (bf16_t)p2, (bf16_t)p3};
        *(bf16x4*)(Pw + (qi * 16 + lr) * 72 + mt * 16 + quad * 4) = pk;
      }

    // ---- P A-frags (wave-private: in-order DS + lgkmcnt, no barrier) ----
    bf16x8 pa[2][2];
#pragma unroll
    for (int qi = 0; qi < 2; ++qi)
#pragma unroll
      for (int kvh = 0; kvh < 2; ++kvh)
        pa[qi][kvh] = *(const bf16x8*)(Pw + (qi * 16 + lr) * 72 + kvh * 32 + quad * 8);

    // ---- O += P @ V : 16 MFMAs ----
#pragma unroll
    for (int t = 0; t < 4; ++t)
#pragma unroll
      for (int qi = 0; qi < 2; ++qi) {
        acc[qi][t] = MFMA_BF16(pa[qi][0], vf[t][0], acc[qi][t], 0, 0, 0);
        acc[qi][t] = MFMA_BF16(pa[qi][1], vf[t][1], acc[qi][t], 0, 0, 0);
      }

    // ---- write prefetched chunk into buf nxt ----
    if (it != 63) {
#pragma unroll
      for (int j = 0; j < 2; ++j) {
        *(bf16x8*)(&Klds[nxt][srow * 72 + scol + j * 8]) = kst[j];
        *(bf16x8*)(&Vlds[nxt][srow * 72 + scol + j * 8]) = vst[j];
      }
    }
    __syncthreads();
  }

  // reduce lsum over the 4 quads
#pragma unroll
  for (int qi = 0; qi < 2; ++qi) {
    lsum[qi] += __shfl_xor(lsum[qi], 16);
    lsum[qi] += __shfl_xor(lsum[qi], 32);
  }

  const int b = bh >> 3, h = bh & 7;
  bf16_t* Ob = Oc + (size_t)b * 4096 * 512 + h * 64;
#pragma unroll
  for (int qi = 0; qi < 2; ++qi) {
    float inv[4];
#pragma unroll
    for (int r = 0; r < 4; ++r)
      inv[r] = 1.0f / __shfl(lsum[qi], quad * 4 + r);
#pragma unroll
    for (int t = 0; t < 4; ++t)
#pragma unroll
      for (int r = 0; r < 4; ++r) {
        const int n = qt0 + qi * 16 + quad * 4 + r;
        Ob[(size_t)n * 512 + t * 16 + lr] = (bf16_t)(acc[qi][t][r] * inv[r]);
      }
  }
}

// ---------------------------------------------------------------------------
extern "C" void kernel_launch(void* const* d_in, const int* in_sizes, int n_in,
                              void* d_out, int out_size, void* d_ws, size_t ws_size,
                              hipStream_t stream)
{
  const float* q  = (const float*)d_in[0];
  const float* k  = (const float*)d_in[1];
  const float* v  = (const float*)d_in[2];
  const float* Wq = (const float*)d_in[3];
  const float* bq = (const float*)d_in[4];
  const float* Wk = (const float*)d_in[5];
  const float* bk = (const float*)d_in[6];
  const float* Wv = (const float*)d_in[7];
  const float* bv = (const float*)d_in[8];
  const float* Wo = (const float*)d_in[9];
  const float* bo = (const float*)d_in[10];

  const size_t HEAD_ELEMS = (size_t)2 * 8 * 4096 * 64;  // 8 MB bf16 each
  bf16_t* Qp = (bf16_t*)d_ws;          // [B,H,N,D], pre-scaled
  bf16_t* Kp = Qp + HEAD_ELEMS;        // [B,H,N,D]
  bf16_t* Vt = Kp + HEAD_ELEMS;        // [B,H,D,N]
  bf16_t* Oc = Vt + HEAD_ELEMS;        // [B,N,E]

  const float qscale = 0.125f * 1.44269504f;  // 1/sqrt(D) * log2(e)

  proj_gemm<true, 0><<<dim3(512), 256, 0, stream>>>((const void*)q, Wq, bq, (void*)Qp, qscale);
  proj_gemm<true, 0><<<dim3(512), 256, 0, stream>>>((const void*)k, Wk, bk, (void*)Kp, 1.0f);
  proj_gemm<true, 1><<<dim3(512), 256, 0, stream>>>((const void*)v, Wv, bv, (void*)Vt, 1.0f);
  flash_attn<<<dim3(16, 32), 256, 0, stream>>>(Qp, Kp, Vt, Oc);
  proj_gemm<false, 2><<<dim3(512), 256, 0, stream>>>((const void*)Oc, Wo, bo, d_out, 1.0f);
}

// Round 10
// 265.777 us; speedup vs baseline: 1.0303x; 1.0303x over previous
//
#include <hip/hip_runtime.h>
#include <hip/hip_bf16.h>
#include <cstddef>

// MHA: B=2, N=4096, E=512, H=8, D=64.
// FUSED QKV projection (one dispatch, 1536 blocks: slice 0=Q,1=K,2=V;
// 128x64 tile, BK=64, dbuf LDS) -> flash v8 (unchanged: 32q/wave, 2
// blocks/CU, reg-prefetch + ds_write staging, stride-72 LDS, no-max softmax,
// Q pre-scaled by 0.125*log2e) -> final proj (f32 out).
// Buffers: Qp/Kp [B,H,N,D], Vt [B,H,D,N], Oc [B,N,E] (all plain layout).

typedef __bf16 bf16_t;
typedef __bf16 bf16x8 __attribute__((ext_vector_type(8)));
typedef __bf16 bf16x4 __attribute__((ext_vector_type(4)));
typedef float  f32x4  __attribute__((ext_vector_type(4)));

#define MFMA_BF16 __builtin_amdgcn_mfma_f32_16x16x32_bf16

static __device__ __forceinline__ bf16x8 cvt2(const float4& a, const float4& b) {
  return bf16x8{(bf16_t)a.x,(bf16_t)a.y,(bf16_t)a.z,(bf16_t)a.w,
                (bf16_t)b.x,(bf16_t)b.y,(bf16_t)b.z,(bf16_t)b.w};
}

// ---------------------------------------------------------------------------
// qkv_proj: all three projections in ONE dispatch. Grid 1536 blocks:
//   slice = l>>9 (0=Q,1=K,2=V), inner = l&511,
//   mtile = ((inner>>6)<<3)|(inner&7), ntile = (inner>>3)&7.
// Per block: C[128x64] = X @ W^T + bias (*scale), BK=64, 4 waves (64x32
// quadrants), double-buffered padded LDS (stride 72).
// Q/K epilogue: bf16 [B,H,N,D] (Q scaled by 0.125*log2e). V: bf16 [B,H,D,N].
// ---------------------------------------------------------------------------
__global__ void __launch_bounds__(256, 2)
qkv_proj(const float* __restrict__ q, const float* __restrict__ k,
         const float* __restrict__ v,
         const float* __restrict__ Wq, const float* __restrict__ bq,
         const float* __restrict__ Wk, const float* __restrict__ bk,
         const float* __restrict__ Wv, const float* __restrict__ bv,
         bf16_t* __restrict__ Qp, bf16_t* __restrict__ Kp,
         bf16_t* __restrict__ Vt, float qscale)
{
  __shared__ __align__(16) bf16_t As[2][128 * 72];
  __shared__ __align__(16) bf16_t Bs[2][64 * 72];
  const int l     = blockIdx.x;                  // 0..1535
  const int slice = l >> 9;                      // 0=Q, 1=K, 2=V
  const int inner = l & 511;
  const int mtile = ((inner >> 6) << 3) | (inner & 7);  // 0..63
  const int ntile = (inner >> 3) & 7;                   // 0..7
  const int tid   = threadIdx.x;
  const int w     = tid >> 6;
  const int lane  = tid & 63;
  const int lr    = lane & 15;
  const int quad  = lane >> 4;
  const int wm    = w & 1;
  const int wn    = w >> 1;
  const int xrow  = tid >> 1, xcol = (tid & 1) << 5;
  const int wrow  = tid >> 2, wcol = (tid & 3) << 4;

  const float* Xf   = (slice == 0) ? q  : (slice == 1) ? k  : v;
  const float* W    = (slice == 0) ? Wq : (slice == 1) ? Wk : Wv;
  const float* bias = (slice == 0) ? bq : (slice == 1) ? bk : bv;
  const float scale = (slice == 0) ? qscale : 1.0f;

  float bvv[2];
#pragma unroll
  for (int ci = 0; ci < 2; ++ci) bvv[ci] = bias[ntile * 64 + wn * 32 + ci * 16 + lr];

  f32x4 acc[4][2] = {};
  float4 xa[8], wa[4];

  // ---- prologue: load k0=0 ----
#pragma unroll
  for (int j = 0; j < 4; ++j) {
    const float* p = Xf + (size_t)(mtile * 128 + xrow) * 512 + xcol + j * 8;
    xa[2*j]   = *(const float4*)p;
    xa[2*j+1] = *(const float4*)(p + 4);
  }
#pragma unroll
  for (int j = 0; j < 2; ++j) {
    const float* pw = W + (size_t)(ntile * 64 + wrow) * 512 + wcol + j * 8;
    wa[2*j]   = *(const float4*)pw;
    wa[2*j+1] = *(const float4*)(pw + 4);
  }
#pragma unroll
  for (int j = 0; j < 4; ++j)
    *(bf16x8*)(&As[0][xrow * 72 + xcol + j * 8]) = cvt2(xa[2*j], xa[2*j+1]);
#pragma unroll
  for (int j = 0; j < 2; ++j)
    *(bf16x8*)(&Bs[0][wrow * 72 + wcol + j * 8]) = cvt2(wa[2*j], wa[2*j+1]);
  __syncthreads();

  for (int it = 0; it < 8; ++it) {
    const int cur = it & 1, nxt = cur ^ 1;
    if (it != 7) {
      const int k0 = (it + 1) << 6;
#pragma unroll
      for (int j = 0; j < 4; ++j) {
        const float* p = Xf + (size_t)(mtile * 128 + xrow) * 512 + k0 + xcol + j * 8;
        xa[2*j]   = *(const float4*)p;
        xa[2*j+1] = *(const float4*)(p + 4);
      }
#pragma unroll
      for (int j = 0; j < 2; ++j) {
        const float* pw = W + (size_t)(ntile * 64 + wrow) * 512 + k0 + wcol + j * 8;
        wa[2*j]   = *(const float4*)pw;
        wa[2*j+1] = *(const float4*)(pw + 4);
      }
    }
    bf16x8 af[4][2], bfr[2][2];
#pragma unroll
    for (int mi = 0; mi < 4; ++mi)
#pragma unroll
      for (int kh = 0; kh < 2; ++kh)
        af[mi][kh] = *(const bf16x8*)(&As[cur][(wm * 64 + mi * 16 + lr) * 72 + (kh * 4 + quad) * 8]);
#pragma unroll
    for (int ci = 0; ci < 2; ++ci)
#pragma unroll
      for (int kh = 0; kh < 2; ++kh)
        bfr[ci][kh] = *(const bf16x8*)(&Bs[cur][(wn * 32 + ci * 16 + lr) * 72 + (kh * 4 + quad) * 8]);
#pragma unroll
    for (int mi = 0; mi < 4; ++mi)
#pragma unroll
      for (int ci = 0; ci < 2; ++ci) {
        acc[mi][ci] = MFMA_BF16(af[mi][0], bfr[ci][0], acc[mi][ci], 0, 0, 0);
        acc[mi][ci] = MFMA_BF16(af[mi][1], bfr[ci][1], acc[mi][ci], 0, 0, 0);
      }
    if (it != 7) {
#pragma unroll
      for (int j = 0; j < 4; ++j)
        *(bf16x8*)(&As[nxt][xrow * 72 + xcol + j * 8]) = cvt2(xa[2*j], xa[2*j+1]);
#pragma unroll
      for (int j = 0; j < 2; ++j)
        *(bf16x8*)(&Bs[nxt][wrow * 72 + wcol + j * 8]) = cvt2(wa[2*j], wa[2*j+1]);
    }
    __syncthreads();
  }

  // C/D layout: col = lane&15 (n), row = quad*4 + reg (m)
  bf16_t* outQK = (slice == 0) ? Qp : Kp;
#pragma unroll
  for (int mi = 0; mi < 4; ++mi) {
    const int gm0 = mtile * 128 + wm * 64 + mi * 16 + quad * 4;
#pragma unroll
    for (int ci = 0; ci < 2; ++ci) {
      const int gc = ntile * 64 + wn * 32 + ci * 16 + lr;
      const int h = gc >> 6, dd = gc & 63;
      if (slice < 2) {
#pragma unroll
        for (int r = 0; r < 4; ++r) {
          const int gm = gm0 + r;
          const int b = gm >> 12, n = gm & 4095;
          outQK[(size_t)((b * 8 + h) * 4096 + n) * 64 + dd] =
              (bf16_t)((acc[mi][ci][r] + bvv[ci]) * scale);
        }
      } else {
        const int b = gm0 >> 12, n0 = gm0 & 4095;  // 4 consecutive n, same b
        bf16x4 pk;
#pragma unroll
        for (int r = 0; r < 4; ++r) pk[r] = (bf16_t)(acc[mi][ci][r] + bvv[ci]);
        *(bf16x4*)(Vt + (size_t)((b * 8 + h) * 64 + dd) * 4096 + n0) = pk;
      }
    }
  }
}

// ---------------------------------------------------------------------------
// o_proj: final projection, f32 out [B,N,E]; X is bf16 Oc [B,N,E].
// Same structure as qkv_proj (128x64 tile, BK=64, dbuf), grid 512.
// ---------------------------------------------------------------------------
__global__ void __launch_bounds__(256, 2)
o_proj(const bf16_t* __restrict__ Xb, const float* __restrict__ W,
       const float* __restrict__ bias, float* __restrict__ out)
{
  __shared__ __align__(16) bf16_t As[2][128 * 72];
  __shared__ __align__(16) bf16_t Bs[2][64 * 72];
  const int l     = blockIdx.x;
  const int mtile = ((l >> 6) << 3) | (l & 7);
  const int ntile = (l >> 3) & 7;
  const int tid   = threadIdx.x;
  const int w     = tid >> 6;
  const int lane  = tid & 63;
  const int lr    = lane & 15;
  const int quad  = lane >> 4;
  const int wm    = w & 1;
  const int wn    = w >> 1;
  const int xrow  = tid >> 1, xcol = (tid & 1) << 5;
  const int wrow  = tid >> 2, wcol = (tid & 3) << 4;

  float bvv[2];
#pragma unroll
  for (int ci = 0; ci < 2; ++ci) bvv[ci] = bias[ntile * 64 + wn * 32 + ci * 16 + lr];

  f32x4 acc[4][2] = {};
  float4 wa[4];
  bf16x8 xb[4];

#pragma unroll
  for (int j = 0; j < 4; ++j)
    xb[j] = *(const bf16x8*)(Xb + (size_t)(mtile * 128 + xrow) * 512 + xcol + j * 8);
#pragma unroll
  for (int j = 0; j < 2; ++j) {
    const float* pw = W + (size_t)(ntile * 64 + wrow) * 512 + wcol + j * 8;
    wa[2*j]   = *(const float4*)pw;
    wa[2*j+1] = *(const float4*)(pw + 4);
  }
#pragma unroll
  for (int j = 0; j < 4; ++j)
    *(bf16x8*)(&As[0][xrow * 72 + xcol + j * 8]) = xb[j];
#pragma unroll
  for (int j = 0; j < 2; ++j)
    *(bf16x8*)(&Bs[0][wrow * 72 + wcol + j * 8]) = cvt2(wa[2*j], wa[2*j+1]);
  __syncthreads();

  for (int it = 0; it < 8; ++it) {
    const int cur = it & 1, nxt = cur ^ 1;
    if (it != 7) {
      const int k0 = (it + 1) << 6;
#pragma unroll
      for (int j = 0; j < 4; ++j)
        xb[j] = *(const bf16x8*)(Xb + (size_t)(mtile * 128 + xrow) * 512 + k0 + xcol + j * 8);
#pragma unroll
      for (int j = 0; j < 2; ++j) {
        const float* pw = W + (size_t)(ntile * 64 + wrow) * 512 + k0 + wcol + j * 8;
        wa[2*j]   = *(const float4*)pw;
        wa[2*j+1] = *(const float4*)(pw + 4);
      }
    }
    bf16x8 af[4][2], bfr[2][2];
#pragma unroll
    for (int mi = 0; mi < 4; ++mi)
#pragma unroll
      for (int kh = 0; kh < 2; ++kh)
        af[mi][kh] = *(const bf16x8*)(&As[cur][(wm * 64 + mi * 16 + lr) * 72 + (kh * 4 + quad) * 8]);
#pragma unroll
    for (int ci = 0; ci < 2; ++ci)
#pragma unroll
      for (int kh = 0; kh < 2; ++kh)
        bfr[ci][kh] = *(const bf16x8*)(&Bs[cur][(wn * 32 + ci * 16 + lr) * 72 + (kh * 4 + quad) * 8]);
#pragma unroll
    for (int mi = 0; mi < 4; ++mi)
#pragma unroll
      for (int ci = 0; ci < 2; ++ci) {
        acc[mi][ci] = MFMA_BF16(af[mi][0], bfr[ci][0], acc[mi][ci], 0, 0, 0);
        acc[mi][ci] = MFMA_BF16(af[mi][1], bfr[ci][1], acc[mi][ci], 0, 0, 0);
      }
    if (it != 7) {
#pragma unroll
      for (int j = 0; j < 4; ++j)
        *(bf16x8*)(&As[nxt][xrow * 72 + xcol + j * 8]) = xb[j];
#pragma unroll
      for (int j = 0; j < 2; ++j)
        *(bf16x8*)(&Bs[nxt][wrow * 72 + wcol + j * 8]) = cvt2(wa[2*j], wa[2*j+1]);
    }
    __syncthreads();
  }

#pragma unroll
  for (int mi = 0; mi < 4; ++mi) {
    const int gm0 = mtile * 128 + wm * 64 + mi * 16 + quad * 4;
#pragma unroll
    for (int ci = 0; ci < 2; ++ci) {
      const int gc = ntile * 64 + wn * 32 + ci * 16 + lr;
#pragma unroll
      for (int r = 0; r < 4; ++r)
        out[(size_t)(gm0 + r) * 512 + gc] = acc[mi][ci][r] + bvv[ci];
    }
  }
}

// ---------------------------------------------------------------------------
// flash_attn v8 (unchanged, measured 100.6 us, LDS-pipe-bound):
// 256 thr = 4 waves, each wave 32 q-rows; grid (16,32) -> 2 blocks/CU.
// KV chunk 64 double-buffered via register-prefetch + ds_write (stride 72).
// Transposed S (S^T = K @ Q^T), fixed m=0 softmax, wave-private P buffer.
// ---------------------------------------------------------------------------
__global__ void __launch_bounds__(256, 2)
flash_attn(const bf16_t* __restrict__ Qp, const bf16_t* __restrict__ Kp,
           const bf16_t* __restrict__ Vt, bf16_t* __restrict__ Oc)
{
  __shared__ __align__(16) bf16_t Klds[2][64 * 72];
  __shared__ __align__(16) bf16_t Vlds[2][64 * 72];
  __shared__ __align__(16) bf16_t Pl[4][32 * 72];

  const int tid  = threadIdx.x;
  const int w    = tid >> 6;
  const int lane = tid & 63, lr = lane & 15, quad = lane >> 4;
  const int bh   = blockIdx.x;
  const int qt0  = blockIdx.y * 128 + w * 32;

  const bf16_t* Qh = Qp + (size_t)bh * 4096 * 64;
  const bf16_t* Kh = Kp + (size_t)bh * 4096 * 64;
  const bf16_t* Vh = Vt + (size_t)bh * 64 * 4096;

  const int srow = w * 16 + (lane >> 2);
  const int scol = (lane & 3) << 4;

  bf16x8 qf[2][2];
#pragma unroll
  for (int qi = 0; qi < 2; ++qi)
#pragma unroll
    for (int kh = 0; kh < 2; ++kh)
      qf[qi][kh] = *(const bf16x8*)(Qh + (size_t)(qt0 + qi * 16 + lr) * 64 + kh * 32 + quad * 8);

  bf16x8 kst[2], vst[2];
#pragma unroll
  for (int j = 0; j < 2; ++j) {
    kst[j] = *(const bf16x8*)(Kh + (size_t)srow * 64 + scol + j * 8);
    vst[j] = *(const bf16x8*)(Vh + (size_t)srow * 4096 + scol + j * 8);
  }
#pragma unroll
  for (int j = 0; j < 2; ++j) {
    *(bf16x8*)(&Klds[0][srow * 72 + scol + j * 8]) = kst[j];
    *(bf16x8*)(&Vlds[0][srow * 72 + scol + j * 8]) = vst[j];
  }
  __syncthreads();

  f32x4 acc[2][4] = {};
  float lsum[2] = {0.f, 0.f};
  const f32x4 zero = {0.f, 0.f, 0.f, 0.f};
  bf16_t* Pw = &Pl[w][0];

  for (int it = 0; it < 64; ++it) {
    const int cur = it & 1, nxt = cur ^ 1;

    if (it != 63) {
      const int kvn = (it + 1) << 6;
#pragma unroll
      for (int j = 0; j < 2; ++j) {
        kst[j] = *(const bf16x8*)(Kh + (size_t)(kvn + srow) * 64 + scol + j * 8);
        vst[j] = *(const bf16x8*)(Vh + (size_t)srow * 4096 + kvn + scol + j * 8);
      }
    }

    bf16x8 kf[4][2];
#pragma unroll
    for (int mt = 0; mt < 4; ++mt)
#pragma unroll
      for (int kh = 0; kh < 2; ++kh)
        kf[mt][kh] = *(const bf16x8*)(&Klds[cur][(mt * 16 + lr) * 72 + (kh * 4 + quad) * 8]);
    bf16x8 vf[4][2];
#pragma unroll
    for (int t = 0; t < 4; ++t)
#pragma unroll
      for (int kvh = 0; kvh < 2; ++kvh)
        vf[t][kvh] = *(const bf16x8*)(&Vlds[cur][(t * 16 + lr) * 72 + (kvh * 4 + quad) * 8]);

    f32x4 sT[4][2];
#pragma unroll
    for (int mt = 0; mt < 4; ++mt)
#pragma unroll
      for (int qi = 0; qi < 2; ++qi) {
        sT[mt][qi] = MFMA_BF16(kf[mt][0], qf[qi][0], zero, 0, 0, 0);
        sT[mt][qi] = MFMA_BF16(kf[mt][1], qf[qi][1], sT[mt][qi], 0, 0, 0);
      }

#pragma unroll
    for (int mt = 0; mt < 4; ++mt)
#pragma unroll
      for (int qi = 0; qi < 2; ++qi) {
        float p0 = __builtin_amdgcn_exp2f(sT[mt][qi][0]);
        float p1 = __builtin_amdgcn_exp2f(sT[mt][qi][1]);
        float p2 = __builtin_amdgcn_exp2f(sT[mt][qi][2]);
        float p3 = __builtin_amdgcn_exp2f(sT[mt][qi][3]);
        lsum[qi] += (p0 + p1) + (p2 + p3);
        bf16x4 pk = {(bf16_t)p0, (bf16_t)p1, (bf16_t)p2, (bf16_t)p3};
        *(bf16x4*)(Pw + (qi * 16 + lr) * 72 + mt * 16 + quad * 4) = pk;
      }

    bf16x8 pa[2][2];
#pragma unroll
    for (int qi = 0; qi < 2; ++qi)
#pragma unroll
      for (int kvh = 0; kvh < 2; ++kvh)
        pa[qi][kvh] = *(const bf16x8*)(Pw + (qi * 16 + lr) * 72 + kvh * 32 + quad * 8);

#pragma unroll
    for (int t = 0; t < 4; ++t)
#pragma unroll
      for (int qi = 0; qi < 2; ++qi) {
        acc[qi][t] = MFMA_BF16(pa[qi][0], vf[t][0], acc[qi][t], 0, 0, 0);
        acc[qi][t] = MFMA_BF16(pa[qi][1], vf[t][1], acc[qi][t], 0, 0, 0);
      }

    if (it != 63) {
#pragma unroll
      for (int j = 0; j < 2; ++j) {
        *(bf16x8*)(&Klds[nxt][srow * 72 + scol + j * 8]) = kst[j];
        *(bf16x8*)(&Vlds[nxt][srow * 72 + scol + j * 8]) = vst[j];
      }
    }
    __syncthreads();
  }

#pragma unroll
  for (int qi = 0; qi < 2; ++qi) {
    lsum[qi] += __shfl_xor(lsum[qi], 16);
    lsum[qi] += __shfl_xor(lsum[qi], 32);
  }

  const int b = bh >> 3, h = bh & 7;
  bf16_t* Ob = Oc + (size_t)b * 4096 * 512 + h * 64;
#pragma unroll
  for (int qi = 0; qi < 2; ++qi) {
    float inv[4];
#pragma unroll
    for (int r = 0; r < 4; ++r)
      inv[r] = 1.0f / __shfl(lsum[qi], quad * 4 + r);
#pragma unroll
    for (int t = 0; t < 4; ++t)
#pragma unroll
      for (int r = 0; r < 4; ++r) {
        const int n = qt0 + qi * 16 + quad * 4 + r;
        Ob[(size_t)n * 512 + t * 16 + lr] = (bf16_t)(acc[qi][t][r] * inv[r]);
      }
  }
}

// ---------------------------------------------------------------------------
extern "C" void kernel_launch(void* const* d_in, const int* in_sizes, int n_in,
                              void* d_out, int out_size, void* d_ws, size_t ws_size,
                              hipStream_t stream)
{
  const float* q  = (const float*)d_in[0];
  const float* k  = (const float*)d_in[1];
  const float* v  = (const float*)d_in[2];
  const float* Wq = (const float*)d_in[3];
  const float* bq = (const float*)d_in[4];
  const float* Wk = (const float*)d_in[5];
  const float* bk = (const float*)d_in[6];
  const float* Wv = (const float*)d_in[7];
  const float* bv = (const float*)d_in[8];
  const float* Wo = (const float*)d_in[9];
  const float* bo = (const float*)d_in[10];

  const size_t HEAD_ELEMS = (size_t)2 * 8 * 4096 * 64;  // 8 MB bf16 each
  bf16_t* Qp = (bf16_t*)d_ws;          // [B,H,N,D], pre-scaled
  bf16_t* Kp = Qp + HEAD_ELEMS;        // [B,H,N,D]
  bf16_t* Vt = Kp + HEAD_ELEMS;        // [B,H,D,N]
  bf16_t* Oc = Vt + HEAD_ELEMS;        // [B,N,E]

  const float qscale = 0.125f * 1.44269504f;  // 1/sqrt(D) * log2(e)

  qkv_proj<<<dim3(1536), 256, 0, stream>>>(q, k, v, Wq, bq, Wk, bk, Wv, bv,
                                           Qp, Kp, Vt, qscale);
  flash_attn<<<dim3(16, 32), 256, 0, stream>>>(Qp, Kp, Vt, Oc);
  o_proj<<<dim3(512), 256, 0, stream>>>(Oc, Wo, bo, (float*)d_out);
}